// Round 20
// baseline (227.884 us; speedup 1.0000x reference)
//
#include <hip/hip_runtime.h>

#define THREADS 256
#define BSH 7
#define BN  128                 // nodes per bucket
#define NBMAX 1024              // max buckets (n <= 131072)
#define NBLK 512                // partition blocks
#define SCAN_WG 1024
#define FCHUNK 8192             // max edges per fill block (chunk = 6250)
#define G1_T 256                // gemm1 threads (1 node per thread)

// ---------------- pass 1: per-(bucket,block) histogram ----------------
__global__ __launch_bounds__(THREADS) void k_hist(const int* __restrict__ dst,
                                                  int* __restrict__ tbl,
                                                  int E, int nb, int chunk) {
    __shared__ int h[NBMAX];
    for (int i = threadIdx.x; i < nb; i += THREADS) h[i] = 0;
    __syncthreads();
    const int e0 = blockIdx.x * chunk;
    const int e1 = min(E, e0 + chunk);
    for (int e = e0 + threadIdx.x; e < e1; e += THREADS)
        atomicAdd(&h[dst[e] >> BSH], 1);
    __syncthreads();
    for (int b = threadIdx.x; b < nb; b += THREADS)
        tbl[b * NBLK + blockIdx.x] = h[b];          // bucket-major
}

// ---------------- in-place scan of tbl ----------------
__global__ __launch_bounds__(SCAN_WG) void k_scanA(int* __restrict__ tbl,
                                                   int* __restrict__ bsum, int T) {
    __shared__ int s[SCAN_WG];
    const int tid = threadIdx.x;
    const int i = blockIdx.x * SCAN_WG + tid;
    int v = (i < T) ? tbl[i] : 0;
    int a = v;
    s[tid] = a; __syncthreads();
    for (int d = 1; d < SCAN_WG; d <<= 1) {
        int add = (tid >= d) ? s[tid - d] : 0;
        __syncthreads();
        a += add; s[tid] = a;
        __syncthreads();
    }
    if (i < T) tbl[i] = a - v;                      // exclusive
    if (tid == SCAN_WG - 1) bsum[blockIdx.x] = a;
}

__global__ __launch_bounds__(SCAN_WG) void k_scanB(int* __restrict__ bsum, int nbs) {
    __shared__ int s[SCAN_WG];
    const int tid = threadIdx.x;
    int v = (tid < nbs) ? bsum[tid] : 0;
    int a = v;
    s[tid] = a; __syncthreads();
    for (int d = 1; d < SCAN_WG; d <<= 1) {
        int add = (tid >= d) ? s[tid - d] : 0;
        __syncthreads();
        a += add; s[tid] = a;
        __syncthreads();
    }
    if (tid < nbs) bsum[tid] = a - v;
}

__global__ __launch_bounds__(SCAN_WG) void k_scanC(int* __restrict__ tbl,
                                                   const int* __restrict__ bsum, int T) {
    const int i = blockIdx.x * SCAN_WG + threadIdx.x;
    if (i < T) tbl[i] += bsum[blockIdx.x];
}

__global__ __launch_bounds__(THREADS) void k_bmeta(const int* __restrict__ tbl,
                                                   int* __restrict__ boff,
                                                   int* __restrict__ bcnt, int nb, int E) {
    const int b = blockIdx.x * THREADS + threadIdx.x;
    if (b < nb) {
        int s0 = tbl[(size_t)b * NBLK];
        int s1 = (b + 1 < nb) ? tbl[(size_t)(b + 1) * NBLK] : E;
        boff[b] = s0; bcnt[b] = s1 - s0;
    }
}

// ---------------- pass 2: block-local counting sort + dense run write-out ----
__global__ __launch_bounds__(THREADS) void k_fill(const int* __restrict__ src,
                                                  const int* __restrict__ dst,
                                                  const int* __restrict__ tbl,
                                                  int* __restrict__ ebuf,
                                                  int E, int nb, int chunk) {
    __shared__ int lh[NBMAX];          // exclusive local offsets
    __shared__ int lw[NBMAX];          // counts, then write ptrs
    __shared__ int part[THREADS];
    __shared__ int sorted[FCHUNK];
    const int t = threadIdx.x, blk = blockIdx.x;

    for (int i = t; i < NBMAX; i += THREADS) lw[i] = 0;
    __syncthreads();

    const int e0 = blk * chunk;
    const int e1 = min(E, e0 + chunk);
    for (int e = e0 + t; e < e1; e += THREADS)
        atomicAdd(&lw[dst[e] >> BSH], 1);
    __syncthreads();

    // two-level exclusive scan over NBMAX bins (4 bins/thread)
    const int base = t * 4;
    int c0 = lw[base], c1 = lw[base + 1], c2 = lw[base + 2], c3 = lw[base + 3];
    int s1 = c0, s2 = c0 + c1, s3 = s2 + c2, tot = s3 + c3;
    part[t] = tot;
    __syncthreads();
    int a = tot;
    for (int d = 1; d < THREADS; d <<= 1) {
        int add = (t >= d) ? part[t - d] : 0;
        __syncthreads();
        a += add; part[t] = a;
        __syncthreads();
    }
    const int pbase = a - tot;                      // exclusive
    lh[base] = pbase; lh[base + 1] = pbase + s1;
    lh[base + 2] = pbase + s2; lh[base + 3] = pbase + s3;
    __syncthreads();
    for (int i = t; i < NBMAX; i += THREADS) lw[i] = lh[i];
    __syncthreads();

    // scatter into LDS (chunk re-read is L2-hot)
    for (int e = e0 + t; e < e1; e += THREADS) {
        int s = src[e], d = dst[e];
        int pos = atomicAdd(&lw[d >> BSH], 1);
        sorted[pos] = (s << BSH) | (d & (BN - 1));
    }
    __syncthreads();

    // dense write-out: one thread per bucket run
    for (int b = t; b < nb; b += THREADS) {
        const int lo = lh[b], hi = lw[b];
        const int gb = tbl[(size_t)b * NBLK + blk];
        for (int i = lo; i < hi; ++i)
            ebuf[gb + (i - lo)] = sorted[i];
    }
}

// ---------------- bucket -> node-sorted CSR + noff + dinv + degree-perm ----
// Also ranks the bucket's nodes by degree (O(128^2) LDS broadcast loop) and
// writes perm so pull waves get degree-uniform node groups (kills trip-count
// divergence: E[max of 16 Poisson(32)] ~ 44 vs mean 32 without it).
__global__ __launch_bounds__(THREADS) void k_nodesort(const int* __restrict__ ebuf,
                                                      const int* __restrict__ boff,
                                                      const int* __restrict__ bcnt,
                                                      int* __restrict__ csr,
                                                      int* __restrict__ noff,
                                                      float* __restrict__ dinv,
                                                      int* __restrict__ perm, int n) {
    __shared__ int hist[BN];
    __shared__ int sc[BN];
    __shared__ int wp[BN];
    __shared__ int dg[BN];
    const int b = blockIdx.x, t = threadIdx.x;
    const int base = b << BSH;
    const int beg = boff[b], m = bcnt[b];

    if (t < BN) hist[t] = 0;
    __syncthreads();
    for (int j = t; j < m; j += THREADS)
        atomicAdd(&hist[ebuf[beg + j] & (BN - 1)], 1);
    __syncthreads();

    if (t < BN) sc[t] = hist[t];
    __syncthreads();
    for (int d = 1; d < BN; d <<= 1) {
        int add = 0;
        if (t < BN && t >= d) add = sc[t - d];
        __syncthreads();
        if (t < BN) sc[t] += add;
        __syncthreads();
    }
    if (t < BN) {
        int excl = sc[t] - hist[t];
        wp[t] = excl;
        int node = base + t;
        if (node <= n) noff[node] = beg + excl;     // node==n -> noff[n]=E (last bucket)
        if (node < n)  dinv[node] = rsqrtf((float)hist[t] + 1.0f);  // +1 self loop
        dg[t] = (node < n) ? hist[t] : 0x7FFFFFFF;  // invalid tail ranks last
    }
    __syncthreads();

    for (int j = t; j < m; j += THREADS) {
        int ent = ebuf[beg + j];
        int pos = atomicAdd(&wp[ent & (BN - 1)], 1);
        csr[beg + pos] = ent >> BSH;
    }

    // degree-rank the bucket's valid nodes -> perm (contiguous ranks)
    if (t < BN && base + t < n) {
        const int my = dg[t];
        int rank = 0;
        #pragma unroll 8
        for (int u = 0; u < BN; ++u) {
            int du = dg[u];
            rank += (du < my) || (du == my && u < t);
        }
        perm[base + rank] = base + t;
    }
}

// ---------------- GEMM1: xw[i][f] = (x[i] @ W1)[f] * dinv[i] ----------------
// One thread = one node, x row direct from global, W1 broadcast from LDS.
__global__ __launch_bounds__(G1_T) void k_gemm1(const float* __restrict__ x,
                                                const float* __restrict__ W1,
                                                const float* __restrict__ dinv,
                                                float* __restrict__ xw, int n) {
    __shared__ float wt[288 * 16];          // raw W1 copy, [k][16]
    const int t = threadIdx.x;

    for (int i = t; i < 288 * 16 / 4; i += G1_T)
        reinterpret_cast<float4*>(wt)[i] = reinterpret_cast<const float4*>(W1)[i];
    __syncthreads();

    const int node = blockIdx.x * G1_T + t;
    if (node >= n) return;

    const float4* xr = reinterpret_cast<const float4*>(x + (size_t)node * 288);
    float4 a0 = {0,0,0,0}, a1 = {0,0,0,0}, a2 = {0,0,0,0}, a3 = {0,0,0,0};

    #pragma unroll 4
    for (int k4 = 0; k4 < 72; ++k4) {
        float4 xv = xr[k4];
        const float* wk = &wt[k4 * 64];     // 4 consecutive ks x 16 f
        #pragma unroll
        for (int kk = 0; kk < 4; ++kk) {
            float xsv = (kk == 0) ? xv.x : (kk == 1) ? xv.y : (kk == 2) ? xv.z : xv.w;
            float4 w0 = *reinterpret_cast<const float4*>(&wk[kk * 16 + 0]);
            float4 w1 = *reinterpret_cast<const float4*>(&wk[kk * 16 + 4]);
            float4 w2 = *reinterpret_cast<const float4*>(&wk[kk * 16 + 8]);
            float4 w3 = *reinterpret_cast<const float4*>(&wk[kk * 16 + 12]);
            a0.x = fmaf(xsv, w0.x, a0.x); a0.y = fmaf(xsv, w0.y, a0.y);
            a0.z = fmaf(xsv, w0.z, a0.z); a0.w = fmaf(xsv, w0.w, a0.w);
            a1.x = fmaf(xsv, w1.x, a1.x); a1.y = fmaf(xsv, w1.y, a1.y);
            a1.z = fmaf(xsv, w1.z, a1.z); a1.w = fmaf(xsv, w1.w, a1.w);
            a2.x = fmaf(xsv, w2.x, a2.x); a2.y = fmaf(xsv, w2.y, a2.y);
            a2.z = fmaf(xsv, w2.z, a2.z); a2.w = fmaf(xsv, w2.w, a2.w);
            a3.x = fmaf(xsv, w3.x, a3.x); a3.y = fmaf(xsv, w3.y, a3.y);
            a3.z = fmaf(xsv, w3.z, a3.z); a3.w = fmaf(xsv, w3.w, a3.w);
        }
    }

    const float dv = dinv[node];
    a0.x *= dv; a0.y *= dv; a0.z *= dv; a0.w *= dv;
    a1.x *= dv; a1.y *= dv; a1.z *= dv; a1.w *= dv;
    a2.x *= dv; a2.y *= dv; a2.z *= dv; a2.w *= dv;
    a3.x *= dv; a3.y *= dv; a3.z *= dv; a3.w *= dv;
    float4* o = reinterpret_cast<float4*>(&xw[(size_t)node * 16]);
    o[0] = a0; o[1] = a1; o[2] = a2; o[3] = a3;
}

// ---------------- layer-1 pull: h1 = relu(segsum*dinv + b1) * dinv ----------------
// 4 lanes per node (node via degree-perm), each owns one float4 of the row.
__global__ __launch_bounds__(THREADS) void k_pullA(const float* __restrict__ xws,
                                                   const int* __restrict__ csr,
                                                   const int* __restrict__ noff,
                                                   const float* __restrict__ dinv,
                                                   const int* __restrict__ perm,
                                                   const float* __restrict__ bias,
                                                   float* __restrict__ out, int n) {
    const int t = blockIdx.x * THREADS + threadIdx.x;
    const int g = t >> 2, q = t & 3;
    if (g >= n) return;
    const int node = perm[g];
    const float4* x4 = reinterpret_cast<const float4*>(xws);
    float4 acc = x4[(size_t)node * 4 + q];          // self loop
    const int beg = noff[node], end = noff[node + 1];
    #pragma unroll 4
    for (int j = beg; j < end; ++j) {
        int s = csr[j];
        float4 v = x4[(size_t)s * 4 + q];
        acc.x += v.x; acc.y += v.y; acc.z += v.z; acc.w += v.w;
    }
    const float dv = dinv[node];
    float4 bb = reinterpret_cast<const float4*>(bias)[q];
    acc.x = fmaxf(fmaf(acc.x, dv, bb.x), 0.f) * dv;
    acc.y = fmaxf(fmaf(acc.y, dv, bb.y), 0.f) * dv;
    acc.z = fmaxf(fmaf(acc.z, dv, bb.z), 0.f) * dv;
    acc.w = fmaxf(fmaf(acc.w, dv, bb.w), 0.f) * dv;
    reinterpret_cast<float4*>(out)[(size_t)node * 4 + q] = acc;
}

// ---------------- layer-2 pull + fused head ----------------
// s2 = segsum(h1)*dinv; out = relu(s2@W2+b2)@Wfc+bfc, via quad-lane shuffles.
__global__ __launch_bounds__(THREADS) void k_pullB(const float* __restrict__ h1,
                                                   const int* __restrict__ csr,
                                                   const int* __restrict__ noff,
                                                   const float* __restrict__ dinv,
                                                   const int* __restrict__ perm,
                                                   const float* __restrict__ W2,
                                                   const float* __restrict__ b2,
                                                   const float* __restrict__ Wfc,
                                                   const float* __restrict__ bfc,
                                                   float* __restrict__ out, int n) {
    __shared__ float w2[16 * 32];
    __shared__ float wf[32 * 7];
    __shared__ float sb2[32];
    __shared__ float sbf[7];
    const int tt = threadIdx.x;
    for (int i = tt; i < 16 * 32; i += THREADS) w2[i] = W2[i];
    for (int i = tt; i < 32 * 7; i += THREADS) wf[i] = Wfc[i];
    if (tt < 32) sb2[tt] = b2[tt];
    if (tt < 7)  sbf[tt] = bfc[tt];
    __syncthreads();

    const int t = blockIdx.x * THREADS + tt;
    const int g = t >> 2, q = t & 3;
    if (g >= n) return;
    const int node = perm[g];

    const float4* x4 = reinterpret_cast<const float4*>(h1);
    float4 acc = x4[(size_t)node * 4 + q];          // self loop
    const int beg = noff[node], end = noff[node + 1];
    #pragma unroll 4
    for (int j = beg; j < end; ++j) {
        int s = csr[j];
        float4 v = x4[(size_t)s * 4 + q];
        acc.x += v.x; acc.y += v.y; acc.z += v.z; acc.w += v.w;
    }
    const float dv = dinv[node];
    float av[4] = {acc.x * dv, acc.y * dv, acc.z * dv, acc.w * dv};

    // all-gather s2[16] across the quad (width-4 shuffles)
    float s2[16];
    #pragma unroll
    for (int r = 0; r < 4; ++r) {
        #pragma unroll
        for (int c = 0; c < 4; ++c)
            s2[r * 4 + c] = __shfl(av[c], r, 4);
    }

    // each lane computes its 8-slice of h[32]
    float h[8];
    #pragma unroll
    for (int oo = 0; oo < 8; ++oo) {
        const int o = q * 8 + oo;
        float a = sb2[o];
        #pragma unroll
        for (int k = 0; k < 16; ++k) a = fmaf(s2[k], w2[k * 32 + o], a);
        h[oo] = fmaxf(a, 0.f);
    }

    // partial head outputs over this lane's h-slice, then quad-reduce
    float po[7];
    #pragma unroll
    for (int o = 0; o < 7; ++o) {
        float a = 0.f;
        #pragma unroll
        for (int oo = 0; oo < 8; ++oo) a = fmaf(h[oo], wf[(q * 8 + oo) * 7 + o], a);
        po[o] = a;
    }
    #pragma unroll
    for (int mask = 1; mask < 4; mask <<= 1) {
        #pragma unroll
        for (int o = 0; o < 7; ++o) po[o] += __shfl_xor(po[o], mask, 4);
    }
    if (q == 0) {
        #pragma unroll
        for (int o = 0; o < 7; ++o) out[(size_t)node * 7 + o] = po[o] + sbf[o];
    }
}

extern "C" void kernel_launch(void* const* d_in, const int* in_sizes, int n_in,
                              void* d_out, int out_size, void* d_ws, size_t ws_size,
                              hipStream_t stream) {
    const float* x   = (const float*)d_in[0];
    const int*   ei  = (const int*)d_in[1];
    const float* W1  = (const float*)d_in[2];
    const float* b1  = (const float*)d_in[3];
    const float* W2  = (const float*)d_in[4];
    const float* b2  = (const float*)d_in[5];
    const float* Wfc = (const float*)d_in[6];
    const float* bfc = (const float*)d_in[7];

    const int n = in_sizes[0] / 288;       // 100000
    const int E = in_sizes[1] / 2;         // 3200000
    const int* src = ei;
    const int* dst = ei + E;
    const int nb = (n + BN - 1) >> BSH;    // 782
    const int T  = nb * NBLK;              // 400384
    const int chunk = (E + NBLK - 1) / NBLK;         // 6250 (<= FCHUNK)
    const int nScan = (T + SCAN_WG - 1) / SCAN_WG;   // 391

    int*   wsI  = (int*)d_ws;
    size_t p = 0;
    int*   tbl  = wsI + p;  p += ((size_t)T + 4) & ~(size_t)3;
    int*   bsum = wsI + p;  p += SCAN_WG;
    int*   boff = wsI + p;  p += NBMAX;
    int*   bcnt = wsI + p;  p += NBMAX;
    int*   ebuf = wsI + p;  p += ((size_t)E + 4) & ~(size_t)3;
    int*   csr  = wsI + p;  p += ((size_t)E + 4) & ~(size_t)3;
    int*   noff = wsI + p;  p += ((size_t)n + 8) & ~(size_t)3;
    int*   perm = wsI + p;  p += ((size_t)n + 4) & ~(size_t)3;
    float* dinv = (float*)(wsI + p);  p += ((size_t)n + 4) & ~(size_t)3;
    float* buf1 = (float*)(wsI + p);  p += (size_t)n * 16;   // xw
    float* buf2 = (float*)(wsI + p);                          // h1
    float* out  = (float*)d_out;

    k_hist <<<NBLK, THREADS, 0, stream>>>(dst, tbl, E, nb, chunk);
    k_scanA<<<nScan, SCAN_WG, 0, stream>>>(tbl, bsum, T);
    k_scanB<<<1, SCAN_WG, 0, stream>>>(bsum, nScan);
    k_scanC<<<nScan, SCAN_WG, 0, stream>>>(tbl, bsum, T);
    k_bmeta<<<(nb + THREADS - 1) / THREADS, THREADS, 0, stream>>>(tbl, boff, bcnt, nb, E);
    k_fill <<<NBLK, THREADS, 0, stream>>>(src, dst, tbl, ebuf, E, nb, chunk);

    k_nodesort<<<nb, THREADS, 0, stream>>>(ebuf, boff, bcnt, csr, noff, dinv, perm, n);

    k_gemm1<<<(n + G1_T - 1) / G1_T, G1_T, 0, stream>>>(x, W1, dinv, buf1, n);

    // layer-1 aggregation + fused relu/bias epilogue (pre-scaled for layer 2)
    k_pullA<<<((size_t)n * 4 + THREADS - 1) / THREADS, THREADS, 0, stream>>>(
        buf1, csr, noff, dinv, perm, b1, buf2, n);

    // layer-2 aggregation + fused head (writes final output directly)
    k_pullB<<<((size_t)n * 4 + THREADS - 1) / THREADS, THREADS, 0, stream>>>(
        buf2, csr, noff, dinv, perm, W2, b2, Wfc, bfc, out, n);
}

// Round 21
// 157.491 us; speedup vs baseline: 1.4470x; 1.4470x over previous
//
#include <hip/hip_runtime.h>
#include <hip/hip_fp16.h>

#define THREADS 256
#define BSH 7
#define BN  128                 // nodes per bucket
#define NBMAX 1024              // max buckets (n <= 131072)
#define NBLK 512                // partition blocks
#define SCAN_WG 1024
#define FCHUNK 8192             // max edges per fill block (chunk = 6250)
#define G1_T 256                // gemm1 threads (1 node per thread)

// ---------------- pass 1: per-(bucket,block) histogram ----------------
__global__ __launch_bounds__(THREADS) void k_hist(const int* __restrict__ dst,
                                                  int* __restrict__ tbl,
                                                  int E, int nb, int chunk) {
    __shared__ int h[NBMAX];
    for (int i = threadIdx.x; i < nb; i += THREADS) h[i] = 0;
    __syncthreads();
    const int e0 = blockIdx.x * chunk;
    const int e1 = min(E, e0 + chunk);
    for (int e = e0 + threadIdx.x; e < e1; e += THREADS)
        atomicAdd(&h[dst[e] >> BSH], 1);
    __syncthreads();
    for (int b = threadIdx.x; b < nb; b += THREADS)
        tbl[b * NBLK + blockIdx.x] = h[b];          // bucket-major
}

// ---------------- in-place scan of tbl ----------------
__global__ __launch_bounds__(SCAN_WG) void k_scanA(int* __restrict__ tbl,
                                                   int* __restrict__ bsum, int T) {
    __shared__ int s[SCAN_WG];
    const int tid = threadIdx.x;
    const int i = blockIdx.x * SCAN_WG + tid;
    int v = (i < T) ? tbl[i] : 0;
    int a = v;
    s[tid] = a; __syncthreads();
    for (int d = 1; d < SCAN_WG; d <<= 1) {
        int add = (tid >= d) ? s[tid - d] : 0;
        __syncthreads();
        a += add; s[tid] = a;
        __syncthreads();
    }
    if (i < T) tbl[i] = a - v;                      // exclusive
    if (tid == SCAN_WG - 1) bsum[blockIdx.x] = a;
}

__global__ __launch_bounds__(SCAN_WG) void k_scanB(int* __restrict__ bsum, int nbs) {
    __shared__ int s[SCAN_WG];
    const int tid = threadIdx.x;
    int v = (tid < nbs) ? bsum[tid] : 0;
    int a = v;
    s[tid] = a; __syncthreads();
    for (int d = 1; d < SCAN_WG; d <<= 1) {
        int add = (tid >= d) ? s[tid - d] : 0;
        __syncthreads();
        a += add; s[tid] = a;
        __syncthreads();
    }
    if (tid < nbs) bsum[tid] = a - v;
}

__global__ __launch_bounds__(SCAN_WG) void k_scanC(int* __restrict__ tbl,
                                                   const int* __restrict__ bsum, int T) {
    const int i = blockIdx.x * SCAN_WG + threadIdx.x;
    if (i < T) tbl[i] += bsum[blockIdx.x];
}

__global__ __launch_bounds__(THREADS) void k_bmeta(const int* __restrict__ tbl,
                                                   int* __restrict__ boff,
                                                   int* __restrict__ bcnt, int nb, int E) {
    const int b = blockIdx.x * THREADS + threadIdx.x;
    if (b < nb) {
        int s0 = tbl[(size_t)b * NBLK];
        int s1 = (b + 1 < nb) ? tbl[(size_t)(b + 1) * NBLK] : E;
        boff[b] = s0; bcnt[b] = s1 - s0;
    }
}

// ---------------- pass 2: block-local counting sort + dense run write-out ----
__global__ __launch_bounds__(THREADS) void k_fill(const int* __restrict__ src,
                                                  const int* __restrict__ dst,
                                                  const int* __restrict__ tbl,
                                                  int* __restrict__ ebuf,
                                                  int E, int nb, int chunk) {
    __shared__ int lh[NBMAX];          // exclusive local offsets
    __shared__ int lw[NBMAX];          // counts, then write ptrs
    __shared__ int part[THREADS];
    __shared__ int sorted[FCHUNK];
    const int t = threadIdx.x, blk = blockIdx.x;

    for (int i = t; i < NBMAX; i += THREADS) lw[i] = 0;
    __syncthreads();

    const int e0 = blk * chunk;
    const int e1 = min(E, e0 + chunk);
    for (int e = e0 + t; e < e1; e += THREADS)
        atomicAdd(&lw[dst[e] >> BSH], 1);
    __syncthreads();

    // two-level exclusive scan over NBMAX bins (4 bins/thread)
    const int base = t * 4;
    int c0 = lw[base], c1 = lw[base + 1], c2 = lw[base + 2], c3 = lw[base + 3];
    int s1 = c0, s2 = c0 + c1, s3 = s2 + c2, tot = s3 + c3;
    part[t] = tot;
    __syncthreads();
    int a = tot;
    for (int d = 1; d < THREADS; d <<= 1) {
        int add = (t >= d) ? part[t - d] : 0;
        __syncthreads();
        a += add; part[t] = a;
        __syncthreads();
    }
    const int pbase = a - tot;                      // exclusive
    lh[base] = pbase; lh[base + 1] = pbase + s1;
    lh[base + 2] = pbase + s2; lh[base + 3] = pbase + s3;
    __syncthreads();
    for (int i = t; i < NBMAX; i += THREADS) lw[i] = lh[i];
    __syncthreads();

    // scatter into LDS (chunk re-read is L2-hot)
    for (int e = e0 + t; e < e1; e += THREADS) {
        int s = src[e], d = dst[e];
        int pos = atomicAdd(&lw[d >> BSH], 1);
        sorted[pos] = (s << BSH) | (d & (BN - 1));
    }
    __syncthreads();

    // dense write-out: one thread per bucket run
    for (int b = t; b < nb; b += THREADS) {
        const int lo = lh[b], hi = lw[b];
        const int gb = tbl[(size_t)b * NBLK + blk];
        for (int i = lo; i < hi; ++i)
            ebuf[gb + (i - lo)] = sorted[i];
    }
}

// ---------------- bucket -> node-sorted CSR + noff + dinv ----------------
__global__ __launch_bounds__(THREADS) void k_nodesort(const int* __restrict__ ebuf,
                                                      const int* __restrict__ boff,
                                                      const int* __restrict__ bcnt,
                                                      int* __restrict__ csr,
                                                      int* __restrict__ noff,
                                                      float* __restrict__ dinv, int n) {
    __shared__ int hist[BN];
    __shared__ int sc[BN];
    __shared__ int wp[BN];
    const int b = blockIdx.x, t = threadIdx.x;
    const int base = b << BSH;
    const int beg = boff[b], m = bcnt[b];

    if (t < BN) hist[t] = 0;
    __syncthreads();
    for (int j = t; j < m; j += THREADS)
        atomicAdd(&hist[ebuf[beg + j] & (BN - 1)], 1);
    __syncthreads();

    if (t < BN) sc[t] = hist[t];
    __syncthreads();
    for (int d = 1; d < BN; d <<= 1) {
        int add = 0;
        if (t < BN && t >= d) add = sc[t - d];
        __syncthreads();
        if (t < BN) sc[t] += add;
        __syncthreads();
    }
    if (t < BN) {
        int excl = sc[t] - hist[t];
        wp[t] = excl;
        int node = base + t;
        if (node <= n) noff[node] = beg + excl;     // node==n -> noff[n]=E (last bucket)
        if (node < n)  dinv[node] = rsqrtf((float)hist[t] + 1.0f);  // +1 self loop
    }
    __syncthreads();

    for (int j = t; j < m; j += THREADS) {
        int ent = ebuf[beg + j];
        int pos = atomicAdd(&wp[ent & (BN - 1)], 1);
        csr[beg + pos] = ent >> BSH;
    }
}

// ---------------- GEMM1: xw[i][f] = fp16((x[i] @ W1)[f] * dinv[i]) ----------
// One thread = one node, x row direct from global, W1 broadcast from LDS.
// Output stored as fp16 (n x 16 half = 3.2 MB -> fits per-XCD L2 for pulls).
__global__ __launch_bounds__(G1_T) void k_gemm1(const float* __restrict__ x,
                                                const float* __restrict__ W1,
                                                const float* __restrict__ dinv,
                                                __half* __restrict__ xw, int n) {
    __shared__ float wt[288 * 16];          // raw W1 copy, [k][16]
    const int t = threadIdx.x;

    for (int i = t; i < 288 * 16 / 4; i += G1_T)
        reinterpret_cast<float4*>(wt)[i] = reinterpret_cast<const float4*>(W1)[i];
    __syncthreads();

    const int node = blockIdx.x * G1_T + t;
    if (node >= n) return;

    const float4* xr = reinterpret_cast<const float4*>(x + (size_t)node * 288);
    float4 a0 = {0,0,0,0}, a1 = {0,0,0,0}, a2 = {0,0,0,0}, a3 = {0,0,0,0};

    #pragma unroll 4
    for (int k4 = 0; k4 < 72; ++k4) {
        float4 xv = xr[k4];
        const float* wk = &wt[k4 * 64];     // 4 consecutive ks x 16 f
        #pragma unroll
        for (int kk = 0; kk < 4; ++kk) {
            float xsv = (kk == 0) ? xv.x : (kk == 1) ? xv.y : (kk == 2) ? xv.z : xv.w;
            float4 w0 = *reinterpret_cast<const float4*>(&wk[kk * 16 + 0]);
            float4 w1 = *reinterpret_cast<const float4*>(&wk[kk * 16 + 4]);
            float4 w2 = *reinterpret_cast<const float4*>(&wk[kk * 16 + 8]);
            float4 w3 = *reinterpret_cast<const float4*>(&wk[kk * 16 + 12]);
            a0.x = fmaf(xsv, w0.x, a0.x); a0.y = fmaf(xsv, w0.y, a0.y);
            a0.z = fmaf(xsv, w0.z, a0.z); a0.w = fmaf(xsv, w0.w, a0.w);
            a1.x = fmaf(xsv, w1.x, a1.x); a1.y = fmaf(xsv, w1.y, a1.y);
            a1.z = fmaf(xsv, w1.z, a1.z); a1.w = fmaf(xsv, w1.w, a1.w);
            a2.x = fmaf(xsv, w2.x, a2.x); a2.y = fmaf(xsv, w2.y, a2.y);
            a2.z = fmaf(xsv, w2.z, a2.z); a2.w = fmaf(xsv, w2.w, a2.w);
            a3.x = fmaf(xsv, w3.x, a3.x); a3.y = fmaf(xsv, w3.y, a3.y);
            a3.z = fmaf(xsv, w3.z, a3.z); a3.w = fmaf(xsv, w3.w, a3.w);
        }
    }

    const float dv = dinv[node];
    float v[16] = {a0.x*dv, a0.y*dv, a0.z*dv, a0.w*dv,
                   a1.x*dv, a1.y*dv, a1.z*dv, a1.w*dv,
                   a2.x*dv, a2.y*dv, a2.z*dv, a2.w*dv,
                   a3.x*dv, a3.y*dv, a3.z*dv, a3.w*dv};
    uint u[8];
    #pragma unroll
    for (int i = 0; i < 8; ++i) {
        __half2 h = __floats2half2_rn(v[2*i], v[2*i+1]);
        u[i] = *reinterpret_cast<uint*>(&h);
    }
    uint4* o = reinterpret_cast<uint4*>(xw + (size_t)node * 16);
    o[0] = make_uint4(u[0], u[1], u[2], u[3]);
    o[1] = make_uint4(u[4], u[5], u[6], u[7]);
}

__device__ __forceinline__ void acc_half4(float* acc, uint2 u) {
    __half2 h0 = *reinterpret_cast<__half2*>(&u.x);
    __half2 h1 = *reinterpret_cast<__half2*>(&u.y);
    float2 f0 = __half22float2(h0);
    float2 f1 = __half22float2(h1);
    acc[0] += f0.x; acc[1] += f0.y; acc[2] += f1.x; acc[3] += f1.y;
}

// ---------------- layer-1 pull: h1 = fp16(relu(segsum*dinv + b1) * dinv) ----
// 4 lanes per node, each owns 4 halfs (8B) of the 32B row. fp32 accumulate.
__global__ __launch_bounds__(THREADS) void k_pullA(const __half* __restrict__ xws,
                                                   const int* __restrict__ csr,
                                                   const int* __restrict__ noff,
                                                   const float* __restrict__ dinv,
                                                   const float* __restrict__ bias,
                                                   __half* __restrict__ out, int n) {
    const int t = blockIdx.x * THREADS + threadIdx.x;
    const int node = t >> 2, q = t & 3;
    if (node >= n) return;
    const uint2* x2 = reinterpret_cast<const uint2*>(xws);
    float acc[4] = {0.f, 0.f, 0.f, 0.f};
    acc_half4(acc, x2[(size_t)node * 4 + q]);       // self loop
    const int beg = noff[node], end = noff[node + 1];
    #pragma unroll 4
    for (int j = beg; j < end; ++j) {
        int s = csr[j];
        acc_half4(acc, x2[(size_t)s * 4 + q]);
    }
    const float dv = dinv[node];
    float4 bb = reinterpret_cast<const float4*>(bias)[q];
    float r0 = fmaxf(fmaf(acc[0], dv, bb.x), 0.f) * dv;
    float r1 = fmaxf(fmaf(acc[1], dv, bb.y), 0.f) * dv;
    float r2 = fmaxf(fmaf(acc[2], dv, bb.z), 0.f) * dv;
    float r3 = fmaxf(fmaf(acc[3], dv, bb.w), 0.f) * dv;
    __half2 h0 = __floats2half2_rn(r0, r1);
    __half2 h1 = __floats2half2_rn(r2, r3);
    uint2 u = make_uint2(*reinterpret_cast<uint*>(&h0), *reinterpret_cast<uint*>(&h1));
    reinterpret_cast<uint2*>(out)[(size_t)node * 4 + q] = u;
}

// ---------------- layer-2 pull + fused head ----------------
// s2 = segsum(h1)*dinv; out = relu(s2@W2+b2)@Wfc+bfc, via quad-lane shuffles.
__global__ __launch_bounds__(THREADS) void k_pullB(const __half* __restrict__ h1,
                                                   const int* __restrict__ csr,
                                                   const int* __restrict__ noff,
                                                   const float* __restrict__ dinv,
                                                   const float* __restrict__ W2,
                                                   const float* __restrict__ b2,
                                                   const float* __restrict__ Wfc,
                                                   const float* __restrict__ bfc,
                                                   float* __restrict__ out, int n) {
    __shared__ float w2[16 * 32];
    __shared__ float wf[32 * 7];
    __shared__ float sb2[32];
    __shared__ float sbf[7];
    const int tt = threadIdx.x;
    for (int i = tt; i < 16 * 32; i += THREADS) w2[i] = W2[i];
    for (int i = tt; i < 32 * 7; i += THREADS) wf[i] = Wfc[i];
    if (tt < 32) sb2[tt] = b2[tt];
    if (tt < 7)  sbf[tt] = bfc[tt];
    __syncthreads();

    const int t = blockIdx.x * THREADS + tt;
    const int node = t >> 2, q = t & 3;
    if (node >= n) return;

    const uint2* x2 = reinterpret_cast<const uint2*>(h1);
    float acc[4] = {0.f, 0.f, 0.f, 0.f};
    acc_half4(acc, x2[(size_t)node * 4 + q]);       // self loop
    const int beg = noff[node], end = noff[node + 1];
    #pragma unroll 4
    for (int j = beg; j < end; ++j) {
        int s = csr[j];
        acc_half4(acc, x2[(size_t)s * 4 + q]);
    }
    const float dv = dinv[node];
    float av[4] = {acc[0] * dv, acc[1] * dv, acc[2] * dv, acc[3] * dv};

    // all-gather s2[16] across the quad (width-4 shuffles)
    float s2[16];
    #pragma unroll
    for (int r = 0; r < 4; ++r) {
        #pragma unroll
        for (int c = 0; c < 4; ++c)
            s2[r * 4 + c] = __shfl(av[c], r, 4);
    }

    // each lane computes its 8-slice of h[32]
    float h[8];
    #pragma unroll
    for (int oo = 0; oo < 8; ++oo) {
        const int o = q * 8 + oo;
        float a = sb2[o];
        #pragma unroll
        for (int k = 0; k < 16; ++k) a = fmaf(s2[k], w2[k * 32 + o], a);
        h[oo] = fmaxf(a, 0.f);
    }

    // partial head outputs over this lane's h-slice, then quad-reduce
    float po[7];
    #pragma unroll
    for (int o = 0; o < 7; ++o) {
        float a = 0.f;
        #pragma unroll
        for (int oo = 0; oo < 8; ++oo) a = fmaf(h[oo], wf[(q * 8 + oo) * 7 + o], a);
        po[o] = a;
    }
    #pragma unroll
    for (int mask = 1; mask < 4; mask <<= 1) {
        #pragma unroll
        for (int o = 0; o < 7; ++o) po[o] += __shfl_xor(po[o], mask, 4);
    }
    if (q == 0) {
        #pragma unroll
        for (int o = 0; o < 7; ++o) out[(size_t)node * 7 + o] = po[o] + sbf[o];
    }
}

extern "C" void kernel_launch(void* const* d_in, const int* in_sizes, int n_in,
                              void* d_out, int out_size, void* d_ws, size_t ws_size,
                              hipStream_t stream) {
    const float* x   = (const float*)d_in[0];
    const int*   ei  = (const int*)d_in[1];
    const float* W1  = (const float*)d_in[2];
    const float* b1  = (const float*)d_in[3];
    const float* W2  = (const float*)d_in[4];
    const float* b2  = (const float*)d_in[5];
    const float* Wfc = (const float*)d_in[6];
    const float* bfc = (const float*)d_in[7];

    const int n = in_sizes[0] / 288;       // 100000
    const int E = in_sizes[1] / 2;         // 3200000
    const int* src = ei;
    const int* dst = ei + E;
    const int nb = (n + BN - 1) >> BSH;    // 782
    const int T  = nb * NBLK;              // 400384
    const int chunk = (E + NBLK - 1) / NBLK;         // 6250 (<= FCHUNK)
    const int nScan = (T + SCAN_WG - 1) / SCAN_WG;   // 391

    int*   wsI  = (int*)d_ws;
    size_t p = 0;
    int*   tbl  = wsI + p;  p += ((size_t)T + 4) & ~(size_t)3;
    int*   bsum = wsI + p;  p += SCAN_WG;
    int*   boff = wsI + p;  p += NBMAX;
    int*   bcnt = wsI + p;  p += NBMAX;
    int*   ebuf = wsI + p;  p += ((size_t)E + 4) & ~(size_t)3;
    int*   csr  = wsI + p;  p += ((size_t)E + 4) & ~(size_t)3;
    int*   noff = wsI + p;  p += ((size_t)n + 8) & ~(size_t)3;
    float* dinv = (float*)(wsI + p);  p += ((size_t)n + 4) & ~(size_t)3;
    __half* xwh = (__half*)(wsI + p); p += (size_t)n * 8;    // n*16 half
    __half* h1h = (__half*)(wsI + p);                         // n*16 half
    float* out  = (float*)d_out;

    k_hist <<<NBLK, THREADS, 0, stream>>>(dst, tbl, E, nb, chunk);
    k_scanA<<<nScan, SCAN_WG, 0, stream>>>(tbl, bsum, T);
    k_scanB<<<1, SCAN_WG, 0, stream>>>(bsum, nScan);
    k_scanC<<<nScan, SCAN_WG, 0, stream>>>(tbl, bsum, T);
    k_bmeta<<<(nb + THREADS - 1) / THREADS, THREADS, 0, stream>>>(tbl, boff, bcnt, nb, E);
    k_fill <<<NBLK, THREADS, 0, stream>>>(src, dst, tbl, ebuf, E, nb, chunk);

    k_nodesort<<<nb, THREADS, 0, stream>>>(ebuf, boff, bcnt, csr, noff, dinv, n);

    k_gemm1<<<(n + G1_T - 1) / G1_T, G1_T, 0, stream>>>(x, W1, dinv, xwh, n);

    // layer-1 aggregation + fused relu/bias epilogue (fp16 L2-resident buffers)
    k_pullA<<<((size_t)n * 4 + THREADS - 1) / THREADS, THREADS, 0, stream>>>(
        xwh, csr, noff, dinv, b1, h1h, n);

    // layer-2 aggregation + fused head (writes final output directly)
    k_pullB<<<((size_t)n * 4 + THREADS - 1) / THREADS, THREADS, 0, stream>>>(
        h1h, csr, noff, dinv, W2, b2, Wfc, bfc, out, n);
}